// Round 8
// baseline (427.736 us; speedup 1.0000x reference)
//
#include <hip/hip_runtime.h>
#include <stdint.h>
#include <type_traits>

typedef __bf16 bf16;
typedef _Float16 f16;
typedef bf16 bf16x8 __attribute__((ext_vector_type(8)));
typedef f16 f16x8 __attribute__((ext_vector_type(8)));
typedef float f32x4 __attribute__((ext_vector_type(4)));

#define LOG2E 1.4426950408889634f
#define SQRT_E 27.712812921102035f

constexpr int BM = 128, BN = 128, BK = 32;
enum { EPI_F32 = 0, EPI_PAIR = 1, EPI_YV = 3 };

__device__ __forceinline__ void async16(const void* g, void* l) {
  __builtin_amdgcn_global_load_lds(
      (__attribute__((address_space(1))) void*)(uintptr_t)g,
      (__attribute__((address_space(3))) void*)l, 16, 0, 0);
}

// C[M,N] = A[M,K] * B[N,K]^T (NT layout, K contiguous in both operands).
// Terms: ah*bh (+ ah*bl if BT==2) (+ al*bh if AT==2, gated by nTwo: blocks with
// bxi >= nTwo > 0 skip the al term — used for fused y|v projection).
// SWZ==1: 1D grid, id%8 XCD round-robin; gxN N-siblings share an M-strip.
template <typename T, typename TO, int AT, int BT, int EPI, int SWZ>
__global__ __launch_bounds__(256)
void gemm_kernel(const T* __restrict__ Ah, const T* __restrict__ Al,
                 const T* __restrict__ Bh, const T* __restrict__ Bl,
                 void* __restrict__ C0, void* __restrict__ C1,
                 void* __restrict__ C2,
                 int K, long lda, long ldb, long ldbl, long ldc,
                 long stA, long stB, long stBl, long stC,
                 int gxN, int gyM, int nTwo) {
  using vec8 = typename std::conditional<std::is_same<T, bf16>::value,
                                         bf16x8, f16x8>::type;
  __shared__ __align__(16) T sAh[BM * BK];
  __shared__ __align__(16) T sBh[BN * BK];
  __shared__ __align__(16) T sAl[AT == 2 ? BM * BK : 8];
  __shared__ __align__(16) T sBl[BT == 2 ? BN * BK : 8];
  __shared__ __align__(16) float sEpi[(EPI == EPI_F32 || EPI == EPI_YV) ? 32 * 128 : 4];

  int bxi, byi, z;
  if constexpr (SWZ) {
    const int id = blockIdx.x;
    const int xcd = id & 7;
    const int j = id >> 3;
    const int s = j / gxN;          // strip index on this XCD
    const int n = j - s * gxN;      // N-sibling
    const int g = xcd + 8 * s;      // global strip id
    bxi = n;
    byi = g % gyM;
    z = g / gyM;
  } else {
    bxi = blockIdx.x; byi = blockIdx.y; z = blockIdx.z;
  }

  const bool twoA = (AT == 2) && ((nTwo <= 0) || (bxi < nTwo));

  const T* pAh = Ah + (long)z * stA;
  const T* pBh = Bh + (long)z * stB;
  const T* pAl = (AT == 2) ? (Al + (long)z * stA) : nullptr;
  const T* pBl = (BT == 2) ? (Bl + (long)z * stBl) : nullptr;

  const int bm = byi * BM;
  const int bn = bxi * BN;
  const int tid = threadIdx.x;
  const int wave = tid >> 6;
  const int lane = tid & 63;
  const int wm = (wave & 1) * 64;
  const int wn = (wave >> 1) * 64;
  const int quad = lane >> 4;
  const int l16 = lane & 15;

  f32x4 acc[4][4] = {};

  const int r0 = tid >> 2;        // staging row 0..63
  const int p0 = (tid & 3) * 8;   // staging k-offset (elements)

  for (int kt = 0; kt < K; kt += BK) {
    __syncthreads();
    {
      const long ka = kt + p0;
      async16(pAh + (long)(bm + r0) * lda + ka,      &sAh[tid * 8]);
      async16(pAh + (long)(bm + 64 + r0) * lda + ka, &sAh[(tid + 256) * 8]);
      async16(pBh + (long)(bn + r0) * ldb + ka,      &sBh[tid * 8]);
      async16(pBh + (long)(bn + 64 + r0) * ldb + ka, &sBh[(tid + 256) * 8]);
      if constexpr (AT == 2) {
        if (twoA) {
          async16(pAl + (long)(bm + r0) * lda + ka,      &sAl[tid * 8]);
          async16(pAl + (long)(bm + 64 + r0) * lda + ka, &sAl[(tid + 256) * 8]);
        }
      }
      if constexpr (BT == 2) {
        async16(pBl + (long)(bn + r0) * ldbl + ka,      &sBl[tid * 8]);
        async16(pBl + (long)(bn + 64 + r0) * ldbl + ka, &sBl[(tid + 256) * 8]);
      }
    }
    __syncthreads();

    vec8 ah[4], al[4];
#pragma unroll
    for (int i = 0; i < 4; ++i) {
      ah[i] = *(const vec8*)&sAh[(wm + i * 16 + l16) * BK + quad * 8];
      if constexpr (AT == 2)
        if (twoA)
          al[i] = *(const vec8*)&sAl[(wm + i * 16 + l16) * BK + quad * 8];
    }
#pragma unroll
    for (int j = 0; j < 4; ++j) {
      const vec8 bh = *(const vec8*)&sBh[(wn + j * 16 + l16) * BK + quad * 8];
      vec8 bl;
      if constexpr (BT == 2)
        bl = *(const vec8*)&sBl[(wn + j * 16 + l16) * BK + quad * 8];
#pragma unroll
      for (int i = 0; i < 4; ++i) {
        acc[i][j] = __builtin_amdgcn_mfma_f32_16x16x32_f16(ah[i], bh, acc[i][j], 0, 0, 0);
        if constexpr (BT == 2)
          acc[i][j] = __builtin_amdgcn_mfma_f32_16x16x32_f16(ah[i], bl, acc[i][j], 0, 0, 0);
        if constexpr (AT == 2)
          if (twoA)
            acc[i][j] = __builtin_amdgcn_mfma_f32_16x16x32_f16(al[i], bh, acc[i][j], 0, 0, 0);
      }
    }
  }

  // ---- epilogues ----
  // C/D frag mapping (m89/m91 verified): col = lane&15, row = quad*4 + reg.
  // EPI_F32 / EPI_YV route tiles through sEpi (4 passes of 32 rows x 128 cols)
  // for coalesced wide stores.
  if constexpr (EPI == EPI_F32) {
    float* C = (float*)C0 + (long)z * stC;
    const int mh = wave & 1;
#pragma unroll
    for (int i = 0; i < 4; ++i) {
#pragma unroll
      for (int j = 0; j < 4; ++j) {
        const int col = wn + j * 16 + l16;
#pragma unroll
        for (int r = 0; r < 4; ++r)
          sEpi[(mh * 16 + quad * 4 + r) * 128 + col] = acc[i][j][r];
      }
      __syncthreads();
      {
        const int lr = tid >> 3;
        const int c0 = (tid & 7) * 4;
        const int grow = bm + ((lr < 16) ? (i * 16 + lr) : (64 + i * 16 + (lr - 16)));
        float* dst = C + (long)grow * ldc + bn;
        const float* srcr = &sEpi[lr * 128];
#pragma unroll
        for (int cc = 0; cc < 4; ++cc)
          *(float4*)(dst + c0 + cc * 32) = *(const float4*)(srcr + c0 + cc * 32);
      }
      __syncthreads();
    }
  } else if constexpr (EPI == EPI_PAIR) {
    // scattered (used only by the tiny MT GEMM)
    TO* Ch = (TO*)C0;
    TO* Cl = (TO*)C1;
#pragma unroll
    for (int i = 0; i < 4; ++i) {
      const int mb = bm + wm + i * 16 + quad * 4;
#pragma unroll
      for (int j = 0; j < 4; ++j) {
        const int n = bn + wn + j * 16 + l16;
#pragma unroll
        for (int r = 0; r < 4; ++r) {
          const float f = acc[i][j][r];
          const TO h = (TO)f;
          const long idx = (long)(mb + r) * ldc + n;
          Ch[idx] = h;
          Cl[idx] = (TO)(f - (float)h);
        }
      }
    }
  } else {  // EPI_YV: bxi < nTwo -> y pair (C0=h, C1=l, ldc); else v -> C2 = vT
    const int mh = wave & 1;
    if (bxi < nTwo) {
      TO* Ch = (TO*)C0;
      TO* Cl = (TO*)C1;
      f16* eH = (f16*)sEpi;          // 32x128 f16
      f16* eL = eH + 32 * 128;
#pragma unroll
      for (int i = 0; i < 4; ++i) {
#pragma unroll
        for (int j = 0; j < 4; ++j) {
          const int col = wn + j * 16 + l16;
#pragma unroll
          for (int r = 0; r < 4; ++r) {
            const float f = acc[i][j][r];
            const f16 h = (f16)f;
            const int li = (mh * 16 + quad * 4 + r) * 128 + col;
            eH[li] = h;
            eL[li] = (f16)(f - (float)h);
          }
        }
        __syncthreads();
        {
          const int lr = tid >> 3;
          const int c0 = (tid & 7) * 16;
          const int grow = bm + ((lr < 16) ? (i * 16 + lr) : (64 + i * 16 + (lr - 16)));
          const long o = (long)grow * ldc + bn + c0;
          const f16* sh = eH + lr * 128 + c0;
          const f16* sl = eL + lr * 128 + c0;
          *(uint4*)((f16*)Ch + o)     = *(const uint4*)sh;
          *(uint4*)((f16*)Ch + o + 8) = *(const uint4*)(sh + 8);
          *(uint4*)((f16*)Cl + o)     = *(const uint4*)sl;
          *(uint4*)((f16*)Cl + o + 8) = *(const uint4*)(sl + 8);
        }
        __syncthreads();
      }
    } else {
      // v: transposed f16 out. vT[8][768][2048]; rows of this block are one batch.
      f16* vTp = (f16*)C2;
      const int e0 = bn - nTwo * BN;
      const long bb = bm >> 11;
      const int mlb = bm & 2047;
#pragma unroll
      for (int i = 0; i < 4; ++i) {
#pragma unroll
        for (int j = 0; j < 4; ++j) {
          const int col = wn + j * 16 + l16;
#pragma unroll
          for (int r = 0; r < 4; ++r)
            sEpi[(mh * 16 + quad * 4 + r) * 128 + col] = acc[i][j][r];
        }
        __syncthreads();
        {
          const int eloc = tid >> 1;       // 0..127
          const int h16 = tid & 1;
          const int mlrun = mlb + (h16 ? (64 + i * 16) : (i * 16));
          union { f16 b[16]; uint4 u[2]; } V;
#pragma unroll
          for (int rr = 0; rr < 16; ++rr)
            V.b[rr] = (f16)sEpi[(h16 * 16 + rr) * 128 + eloc];
          f16* dst = vTp + (bb * 768 + e0 + eloc) * 2048 + mlrun;
          *(uint4*)dst = V.u[0];
          *(uint4*)(dst + 8) = V.u[1];
        }
        __syncthreads();
      }
    }
  }
}

// One block per score row (2048 fp32). Writes normalized p * (1/sqrt(768)) as
// f16 IN-PLACE into the first quarter of the row's fp32 storage.
__global__ __launch_bounds__(256)
void softmax_kernel(float* __restrict__ sc) {
  __shared__ float red[4];
  float* srow = sc + (long)blockIdx.x * 2048;
  const int tid = threadIdx.x;
  const int wave = tid >> 6;
  const int lane = tid & 63;
  const float4 v0 = *(const float4*)(srow + tid * 4);
  const float4 v1 = *(const float4*)(srow + 1024 + tid * 4);
  float mx = fmaxf(fmaxf(fmaxf(v0.x, v0.y), fmaxf(v0.z, v0.w)),
                   fmaxf(fmaxf(v1.x, v1.y), fmaxf(v1.z, v1.w)));
#pragma unroll
  for (int o = 32; o >= 1; o >>= 1) mx = fmaxf(mx, __shfl_xor(mx, o));
  if (lane == 0) red[wave] = mx;
  __syncthreads();
  mx = fmaxf(fmaxf(red[0], red[1]), fmaxf(red[2], red[3]));
  const float e0 = exp2f((v0.x - mx) * LOG2E);
  const float e1 = exp2f((v0.y - mx) * LOG2E);
  const float e2 = exp2f((v0.z - mx) * LOG2E);
  const float e3 = exp2f((v0.w - mx) * LOG2E);
  const float e4 = exp2f((v1.x - mx) * LOG2E);
  const float e5 = exp2f((v1.y - mx) * LOG2E);
  const float e6 = exp2f((v1.z - mx) * LOG2E);
  const float e7 = exp2f((v1.w - mx) * LOG2E);
  float s = ((e0 + e1) + (e2 + e3)) + ((e4 + e5) + (e6 + e7));
#pragma unroll
  for (int o = 32; o >= 1; o >>= 1) s += __shfl_xor(s, o);
  __syncthreads();  // everyone done reading red[] for max
  if (lane == 0) red[wave] = s;
  __syncthreads();
  s = red[0] + red[1] + red[2] + red[3];
  const float inv = 1.0f / (s * SQRT_E);
  f16* prow = (f16*)srow;
  union { f16 b[4]; uint2 u; } P;
  P.b[0] = (f16)(e0 * inv); P.b[1] = (f16)(e1 * inv);
  P.b[2] = (f16)(e2 * inv); P.b[3] = (f16)(e3 * inv);
  *(uint2*)(prow + tid * 4) = P.u;
  P.b[0] = (f16)(e4 * inv); P.b[1] = (f16)(e5 * inv);
  P.b[2] = (f16)(e6 * inv); P.b[3] = (f16)(e7 * inv);
  *(uint2*)(prow + 1024 + tid * 4) = P.u;
}

// Fused prep: blocks [0,12864): fp32->f16 split of x (hi/lo) and Wv (hi);
// blocks [12864,13152): 64x64-tile transpose+split of Wq/Wk -> WT[d][e] pairs.
__global__ __launch_bounds__(256)
void prep_kernel(const float4* __restrict__ x, const float4* __restrict__ wv,
                 const float* __restrict__ Wq, const float* __restrict__ Wk,
                 uint2* __restrict__ xh, uint2* __restrict__ xl,
                 uint2* __restrict__ wvh,
                 f16* __restrict__ qTh, f16* __restrict__ qTl,
                 f16* __restrict__ kTh, f16* __restrict__ kTl) {
  __shared__ float tile[64][65];
  constexpr int NX = 3145728;   // x float4 count
  constexpr int NWV = 147456;   // Wv float4 count
  const int t = threadIdx.x;
  if (blockIdx.x < 12864) {
    const int i = blockIdx.x * 256 + t;
    float4 v;
    uint2 *dh, *dl;
    if (i < NX) {
      v = x[i]; dh = xh + i; dl = xl + i;
    } else {
      const int m = i - NX;
      if (m >= NWV) return;
      v = wv[m]; dh = wvh + m; dl = nullptr;
    }
    const f16 h0 = (f16)v.x, h1 = (f16)v.y, h2 = (f16)v.z, h3 = (f16)v.w;
    union { f16 b[4]; uint2 u; } P;
    P.b[0] = h0; P.b[1] = h1; P.b[2] = h2; P.b[3] = h3;
    *dh = P.u;
    if (dl != nullptr) {
      P.b[0] = (f16)(v.x - (float)h0);
      P.b[1] = (f16)(v.y - (float)h1);
      P.b[2] = (f16)(v.z - (float)h2);
      P.b[3] = (f16)(v.w - (float)h3);
      *dl = P.u;
    }
    return;
  }
  const int bid = blockIdx.x - 12864;   // 0..287
  const int zz = bid / 144;
  const int r2 = bid - zz * 144;
  const int byy = r2 / 12, bxx = r2 - (r2 / 12) * 12;
  const float* src = zz ? Wk : Wq;
  f16* dh = zz ? kTh : qTh;
  f16* dl = zz ? kTl : qTl;
  const int e0 = byy * 64, d0 = bxx * 64;
  const int r = t >> 2;            // 0..63
  const int c4 = (t & 3) * 16;     // 0,16,32,48
  const float4* s4 = (const float4*)(src + (long)(e0 + r) * 768 + d0 + c4);
#pragma unroll
  for (int g = 0; g < 4; ++g) {
    const float4 v = s4[g];
    tile[r][c4 + g * 4 + 0] = v.x;
    tile[r][c4 + g * 4 + 1] = v.y;
    tile[r][c4 + g * 4 + 2] = v.z;
    tile[r][c4 + g * 4 + 3] = v.w;
  }
  __syncthreads();
  union { f16 b[8]; uint4 u; } H0, H1, L0, L1;
#pragma unroll
  for (int i = 0; i < 16; ++i) {
    const float v = tile[c4 + i][r];
    const f16 h = (f16)v;
    const f16 l = (f16)(v - (float)h);
    if (i < 8) { H0.b[i] = h; L0.b[i] = l; }
    else       { H1.b[i - 8] = h; L1.b[i - 8] = l; }
  }
  const long o = (long)(d0 + r) * 768 + e0 + c4;
  *(uint4*)(dh + o) = H0.u;  *(uint4*)(dh + o + 8) = H1.u;
  *(uint4*)(dl + o) = L0.u;  *(uint4*)(dl + o + 8) = L1.u;
}

extern "C" void kernel_launch(void* const* d_in, const int* in_sizes, int n_in,
                              void* d_out, int out_size, void* d_ws, size_t ws_size,
                              hipStream_t stream) {
  const float* x  = (const float*)d_in[0];
  const float* Wq = (const float*)d_in[1];
  const float* Wk = (const float*)d_in[2];
  const float* Wv = (const float*)d_in[3];
  float* out = (float*)d_out;
  char* ws = (char*)d_ws;

  // ---- workspace layout (bytes) ----
  // persistent through phase 2: yh, yl, xh [16384,768] f16 + vT [8][768][2048] f16
  const size_t SZ = 25165824;      // 16384*768*2
  f16* yh = (f16*)(ws + 0 * SZ);
  f16* yl = (f16*)(ws + 1 * SZ);
  f16* xh = (f16*)(ws + 2 * SZ);
  f16* vT = (f16*)(ws + 3 * SZ);
  const size_t PERS = 4 * SZ;      // 100663296
  // phase-1 temps (dead after projections); scores slabs overlay them
  const size_t WT = 1179648;       // 768*768 f16
  f16* xl   = (f16*)(ws + PERS);
  f16* wqTh = (f16*)(ws + PERS + SZ);
  f16* wqTl = (f16*)(ws + PERS + SZ + 1 * WT);
  f16* wkTh = (f16*)(ws + PERS + SZ + 2 * WT);
  f16* wkTl = (f16*)(ws + PERS + SZ + 3 * WT);
  f16* mtH  = (f16*)(ws + PERS + SZ + 4 * WT);  // [Mt ; Wv] concat base
  f16* wvh  = (f16*)(ws + PERS + SZ + 5 * WT);  // = mtH + 768*768
  f16* mtL  = (f16*)(ws + PERS + SZ + 6 * WT);
  float* scores = (float*)(ws + PERS);

  long avail = (long)ws_size - (long)PERS;
  int nb = (int)(avail / 16777216);  // fp32 [2048,2048] score slabs that fit
  if (nb < 1) nb = 1;
  if (nb > 8) nb = 8;

  // ---- phase 1 ----
  prep_kernel<<<13152, 256, 0, stream>>>(
      (const float4*)x, (const float4*)Wv, Wq, Wk,
      (uint2*)xh, (uint2*)xl, (uint2*)wvh, wqTh, wqTl, wkTh, wkTl);

  // M^T[d'][d] = sum_e WkT[d'][e] * WqT[d][e]  (3-term, f16 pair out)
  gemm_kernel<f16, f16, 2, 2, EPI_PAIR, 0><<<dim3(6, 6, 1), 256, 0, stream>>>(
      wkTh, wkTl, wqTh, wqTl, (void*)mtH, (void*)mtL, nullptr,
      768, 768, 768, 768, 768, 0, 0, 0, 0, 0, 0, 0);

  // fused y|v projection: A = x (hi/lo), B = [Mt_h ; Wv_h] [1536,768].
  // bxi<6: y = (xh+xl)*Mt^T -> yh/yl pair. bxi>=6: v = xh*Wv^T -> vT transposed.
  gemm_kernel<f16, f16, 2, 1, EPI_YV, 1><<<1536, 256, 0, stream>>>(
      xh, xl, mtH, nullptr, (void*)yh, (void*)yl, (void*)vT,
      768, 768, 768, 0, 768, 0, 0, 0, 0, 12, 128, 6);

  // ---- phase 2: scores -> softmax -> PV ----
  const long RS = 1572864;   // 2048*768 (y/x batch stride, elements)
  const long VTS = 1572864;  // 768*2048
  for (int b0 = 0; b0 < 8; b0 += nb) {
    const int nbg = (8 - b0 < nb) ? (8 - b0) : nb;
    // S = yh * xh^T  (1-term), XCD-swizzled
    gemm_kernel<f16, float, 1, 1, EPI_F32, 1><<<256 * nbg, 256, 0, stream>>>(
        yh + (long)b0 * RS, nullptr, xh + (long)b0 * RS, nullptr,
        (void*)scores, nullptr, nullptr,
        768, 768, 768, 0, 2048, RS, RS, 0, 4194304L, 16, 16, 0);
    softmax_kernel<<<nbg * 2048, 256, 0, stream>>>(scores);
    // O = P * vT^T  (P f16 rows embedded in fp32 score rows, pitch 4096 elems)
    gemm_kernel<f16, float, 1, 1, EPI_F32, 1><<<96 * nbg, 256, 0, stream>>>(
        (const f16*)scores, nullptr, vT + (long)b0 * VTS, nullptr,
        (void*)(out + (long)b0 * 1572864), nullptr, nullptr,
        2048, 4096, 2048, 0, 768, 8388608L, VTS, 0, 1572864L, 6, 16, 0);
  }
}

// Round 9
// 422.104 us; speedup vs baseline: 1.0133x; 1.0133x over previous
//
#include <hip/hip_runtime.h>
#include <stdint.h>

typedef _Float16 f16;
typedef f16 f16x8 __attribute__((ext_vector_type(8)));
typedef float f32x16 __attribute__((ext_vector_type(16)));

#define LOG2E 1.4426950408889634f
#define SQRT_E 27.712812921102035f

constexpr int BM = 128, BN = 128, BK = 32;
enum { EPI_F32 = 0, EPI_PAIR = 1, EPI_VT = 2 };

__device__ __forceinline__ void async16(const void* g, void* l) {
  __builtin_amdgcn_global_load_lds(
      (__attribute__((address_space(1))) void*)(uintptr_t)g,
      (__attribute__((address_space(3))) void*)l, 16, 0, 0);
}

__device__ __forceinline__ f32x16 mfma32(f16x8 a, f16x8 b, f32x16 c) {
  return __builtin_amdgcn_mfma_f32_32x32x16_f16(a, b, c, 0, 0, 0);
}

// C[M,N] = A[M,K] * B[N,K]^T (NT layout, K contiguous in both operands).
// 32x32x16 MFMA: per wave 64x64 = 2x2 tiles of 32x32, 2 K-halves per BK=32.
// A-frag: m = lane&31, k = (lane>>5)*8 + j (analog of verified 16x16 layout).
// C/D [m74/m101 verified]: col = lane&31, row = (reg&3) + 8*(reg>>2) + 4*(lane>>5).
// Terms: ah*bh (+ ah*bl if BT==2) (+ al*bh if AT==2).
// SWZ==1: 1D grid, id%8 XCD round-robin; gxN N-siblings share an M-strip.
template <int AT, int BT, int EPI, int SWZ>
__global__ __launch_bounds__(256)
void gemm_kernel(const f16* __restrict__ Ah, const f16* __restrict__ Al,
                 const f16* __restrict__ Bh, const f16* __restrict__ Bl,
                 void* __restrict__ C0, void* __restrict__ C1,
                 int K, long lda, long ldb, long ldbl, long ldc,
                 long stA, long stB, long stBl, long stC,
                 int gxN, int gyM) {
  __shared__ __align__(16) f16 sAh[BM * BK];
  __shared__ __align__(16) f16 sBh[BN * BK];
  __shared__ __align__(16) f16 sAl[AT == 2 ? BM * BK : 8];
  __shared__ __align__(16) f16 sBl[BT == 2 ? BN * BK : 8];

  int bxi, byi, z;
  if constexpr (SWZ) {
    const int id = blockIdx.x;
    const int xcd = id & 7;
    const int j = id >> 3;
    const int s = j / gxN;          // strip index on this XCD
    const int n = j - s * gxN;      // N-sibling
    const int g = xcd + 8 * s;      // global strip id
    bxi = n;
    byi = g % gyM;
    z = g / gyM;
  } else {
    bxi = blockIdx.x; byi = blockIdx.y; z = blockIdx.z;
  }

  const f16* pAh = Ah + (long)z * stA;
  const f16* pBh = Bh + (long)z * stB;
  const f16* pAl = (AT == 2) ? (Al + (long)z * stA) : nullptr;
  const f16* pBl = (BT == 2) ? (Bl + (long)z * stBl) : nullptr;

  const int bm = byi * BM;
  const int bn = bxi * BN;
  const int tid = threadIdx.x;
  const int wave = tid >> 6;
  const int lane = tid & 63;
  const int wm = (wave & 1) * 64;
  const int wn = (wave >> 1) * 64;
  const int l31 = lane & 31;
  const int h = lane >> 5;          // K-half within fragment

  f32x16 acc[2][2] = {};

  const int r0 = tid >> 2;        // staging row 0..63
  const int p0 = (tid & 3) * 8;   // staging k-offset (elements)

  for (int kt = 0; kt < K; kt += BK) {
    __syncthreads();
    {
      const long ka = kt + p0;
      async16(pAh + (long)(bm + r0) * lda + ka,      &sAh[tid * 8]);
      async16(pAh + (long)(bm + 64 + r0) * lda + ka, &sAh[(tid + 256) * 8]);
      async16(pBh + (long)(bn + r0) * ldb + ka,      &sBh[tid * 8]);
      async16(pBh + (long)(bn + 64 + r0) * ldb + ka, &sBh[(tid + 256) * 8]);
      if constexpr (AT == 2) {
        async16(pAl + (long)(bm + r0) * lda + ka,      &sAl[tid * 8]);
        async16(pAl + (long)(bm + 64 + r0) * lda + ka, &sAl[(tid + 256) * 8]);
      }
      if constexpr (BT == 2) {
        async16(pBl + (long)(bn + r0) * ldbl + ka,      &sBl[tid * 8]);
        async16(pBl + (long)(bn + 64 + r0) * ldbl + ka, &sBl[(tid + 256) * 8]);
      }
    }
    __syncthreads();

    // fragment loads: [m-tile][k-half], 8 contiguous f16 each (ds_read_b128)
    f16x8 a[2][2], av[2][2], b[2][2], bv[2][2];
#pragma unroll
    for (int i = 0; i < 2; ++i)
#pragma unroll
      for (int kk = 0; kk < 2; ++kk) {
        const int off = (wm + i * 32 + l31) * BK + kk * 16 + h * 8;
        a[i][kk] = *(const f16x8*)&sAh[off];
        if constexpr (AT == 2) av[i][kk] = *(const f16x8*)&sAl[off];
      }
#pragma unroll
    for (int j = 0; j < 2; ++j)
#pragma unroll
      for (int kk = 0; kk < 2; ++kk) {
        const int off = (wn + j * 32 + l31) * BK + kk * 16 + h * 8;
        b[j][kk] = *(const f16x8*)&sBh[off];
        if constexpr (BT == 2) bv[j][kk] = *(const f16x8*)&sBl[off];
      }
#pragma unroll
    for (int j = 0; j < 2; ++j)
#pragma unroll
      for (int i = 0; i < 2; ++i) {
#pragma unroll
        for (int kk = 0; kk < 2; ++kk) {
          acc[i][j] = mfma32(a[i][kk], b[j][kk], acc[i][j]);
          if constexpr (BT == 2) acc[i][j] = mfma32(a[i][kk], bv[j][kk], acc[i][j]);
          if constexpr (AT == 2) acc[i][j] = mfma32(av[i][kk], b[j][kk], acc[i][j]);
        }
      }
  }

  // ---- epilogues (32x32 C/D layout) ----
  if constexpr (EPI == EPI_F32) {
    float* C = (float*)C0 + (long)z * stC;
#pragma unroll
    for (int i = 0; i < 2; ++i) {
      const int rb = bm + wm + i * 32 + 4 * h;
#pragma unroll
      for (int j = 0; j < 2; ++j) {
        const int n = bn + wn + j * 32 + l31;
#pragma unroll
        for (int g = 0; g < 4; ++g) {
          const int row = rb + 8 * g;
#pragma unroll
          for (int r = 0; r < 4; ++r)
            C[(long)(row + r) * ldc + n] = acc[i][j][4 * g + r];
        }
      }
    }
  } else if constexpr (EPI == EPI_PAIR) {
    f16* Ch = (f16*)C0;
    f16* Cl = (f16*)C1;
#pragma unroll
    for (int i = 0; i < 2; ++i) {
      const int rb = bm + wm + i * 32 + 4 * h;
#pragma unroll
      for (int j = 0; j < 2; ++j) {
        const int n = bn + wn + j * 32 + l31;
#pragma unroll
        for (int g = 0; g < 4; ++g) {
          const int row = rb + 8 * g;
#pragma unroll
          for (int r = 0; r < 4; ++r) {
            const float f = acc[i][j][4 * g + r];
            const f16 hi = (f16)f;
            const long idx = (long)(row + r) * ldc + n;
            Ch[idx] = hi;
            Cl[idx] = (f16)(f - (float)hi);
          }
        }
      }
    }
  } else {  // EPI_VT: C0 = vT [8][768][2048], global row m -> (m>>11, m&2047)
    f16* vT = (f16*)C0;
#pragma unroll
    for (int i = 0; i < 2; ++i) {
      const int mg = bm + wm + i * 32;
      const long bb = mg >> 11;
      const int ml = (mg & 2047) + 4 * h;
#pragma unroll
      for (int j = 0; j < 2; ++j) {
        const int e = bn + wn + j * 32 + l31;
        f16* dste = vT + (bb * 768 + e) * 2048;
#pragma unroll
        for (int g = 0; g < 4; ++g) {
          union { f16 b4[4]; uint2 u; } P;
#pragma unroll
          for (int r = 0; r < 4; ++r) P.b4[r] = (f16)acc[i][j][4 * g + r];
          *(uint2*)(dste + ml + 8 * g) = P.u;
        }
      }
    }
  }
}

// One block per score row (2048 fp32). Writes normalized p * (1/sqrt(768)) as
// f16 IN-PLACE into the first quarter of the row's fp32 storage.
__global__ __launch_bounds__(256)
void softmax_kernel(float* __restrict__ sc) {
  __shared__ float red[4];
  float* srow = sc + (long)blockIdx.x * 2048;
  const int tid = threadIdx.x;
  const int wave = tid >> 6;
  const int lane = tid & 63;
  const float4 v0 = *(const float4*)(srow + tid * 4);
  const float4 v1 = *(const float4*)(srow + 1024 + tid * 4);
  float mx = fmaxf(fmaxf(fmaxf(v0.x, v0.y), fmaxf(v0.z, v0.w)),
                   fmaxf(fmaxf(v1.x, v1.y), fmaxf(v1.z, v1.w)));
#pragma unroll
  for (int o = 32; o >= 1; o >>= 1) mx = fmaxf(mx, __shfl_xor(mx, o));
  if (lane == 0) red[wave] = mx;
  __syncthreads();
  mx = fmaxf(fmaxf(red[0], red[1]), fmaxf(red[2], red[3]));
  const float e0 = exp2f((v0.x - mx) * LOG2E);
  const float e1 = exp2f((v0.y - mx) * LOG2E);
  const float e2 = exp2f((v0.z - mx) * LOG2E);
  const float e3 = exp2f((v0.w - mx) * LOG2E);
  const float e4 = exp2f((v1.x - mx) * LOG2E);
  const float e5 = exp2f((v1.y - mx) * LOG2E);
  const float e6 = exp2f((v1.z - mx) * LOG2E);
  const float e7 = exp2f((v1.w - mx) * LOG2E);
  float s = ((e0 + e1) + (e2 + e3)) + ((e4 + e5) + (e6 + e7));
#pragma unroll
  for (int o = 32; o >= 1; o >>= 1) s += __shfl_xor(s, o);
  __syncthreads();  // everyone done reading red[] for max
  if (lane == 0) red[wave] = s;
  __syncthreads();
  s = red[0] + red[1] + red[2] + red[3];
  const float inv = 1.0f / (s * SQRT_E);
  f16* prow = (f16*)srow;
  union { f16 b[4]; uint2 u; } P;
  P.b[0] = (f16)(e0 * inv); P.b[1] = (f16)(e1 * inv);
  P.b[2] = (f16)(e2 * inv); P.b[3] = (f16)(e3 * inv);
  *(uint2*)(prow + tid * 4) = P.u;
  P.b[0] = (f16)(e4 * inv); P.b[1] = (f16)(e5 * inv);
  P.b[2] = (f16)(e6 * inv); P.b[3] = (f16)(e7 * inv);
  *(uint2*)(prow + 1024 + tid * 4) = P.u;
}

// Fused prep: blocks [0,12864): fp32->f16 split of x (hi/lo) and Wv (hi);
// blocks [12864,13152): 64x64-tile transpose+split of Wq/Wk -> WT[d][e] pairs.
__global__ __launch_bounds__(256)
void prep_kernel(const float4* __restrict__ x, const float4* __restrict__ wv,
                 const float* __restrict__ Wq, const float* __restrict__ Wk,
                 uint2* __restrict__ xh, uint2* __restrict__ xl,
                 uint2* __restrict__ wvh,
                 f16* __restrict__ qTh, f16* __restrict__ qTl,
                 f16* __restrict__ kTh, f16* __restrict__ kTl) {
  __shared__ float tile[64][65];
  constexpr int NX = 3145728;   // x float4 count
  constexpr int NWV = 147456;   // Wv float4 count
  const int t = threadIdx.x;
  if (blockIdx.x < 12864) {
    const int i = blockIdx.x * 256 + t;
    float4 v;
    uint2 *dh, *dl;
    if (i < NX) {
      v = x[i]; dh = xh + i; dl = xl + i;
    } else {
      const int m = i - NX;
      if (m >= NWV) return;
      v = wv[m]; dh = wvh + m; dl = nullptr;
    }
    const f16 h0 = (f16)v.x, h1 = (f16)v.y, h2 = (f16)v.z, h3 = (f16)v.w;
    union { f16 b[4]; uint2 u; } P;
    P.b[0] = h0; P.b[1] = h1; P.b[2] = h2; P.b[3] = h3;
    *dh = P.u;
    if (dl != nullptr) {
      P.b[0] = (f16)(v.x - (float)h0);
      P.b[1] = (f16)(v.y - (float)h1);
      P.b[2] = (f16)(v.z - (float)h2);
      P.b[3] = (f16)(v.w - (float)h3);
      *dl = P.u;
    }
    return;
  }
  const int bid = blockIdx.x - 12864;   // 0..287
  const int zz = bid / 144;
  const int r2 = bid - zz * 144;
  const int byy = r2 / 12, bxx = r2 - (r2 / 12) * 12;
  const float* src = zz ? Wk : Wq;
  f16* dh = zz ? kTh : qTh;
  f16* dl = zz ? kTl : qTl;
  const int e0 = byy * 64, d0 = bxx * 64;
  const int r = t >> 2;            // 0..63
  const int c4 = (t & 3) * 16;     // 0,16,32,48
  const float4* s4 = (const float4*)(src + (long)(e0 + r) * 768 + d0 + c4);
#pragma unroll
  for (int g = 0; g < 4; ++g) {
    const float4 v = s4[g];
    tile[r][c4 + g * 4 + 0] = v.x;
    tile[r][c4 + g * 4 + 1] = v.y;
    tile[r][c4 + g * 4 + 2] = v.z;
    tile[r][c4 + g * 4 + 3] = v.w;
  }
  __syncthreads();
  union { f16 b[8]; uint4 u; } H0, H1, L0, L1;
#pragma unroll
  for (int i = 0; i < 16; ++i) {
    const float v = tile[c4 + i][r];
    const f16 h = (f16)v;
    const f16 l = (f16)(v - (float)h);
    if (i < 8) { H0.b[i] = h; L0.b[i] = l; }
    else       { H1.b[i - 8] = h; L1.b[i - 8] = l; }
  }
  const long o = (long)(d0 + r) * 768 + e0 + c4;
  *(uint4*)(dh + o) = H0.u;  *(uint4*)(dh + o + 8) = H1.u;
  *(uint4*)(dl + o) = L0.u;  *(uint4*)(dl + o + 8) = L1.u;
}

extern "C" void kernel_launch(void* const* d_in, const int* in_sizes, int n_in,
                              void* d_out, int out_size, void* d_ws, size_t ws_size,
                              hipStream_t stream) {
  const float* x  = (const float*)d_in[0];
  const float* Wq = (const float*)d_in[1];
  const float* Wk = (const float*)d_in[2];
  const float* Wv = (const float*)d_in[3];
  float* out = (float*)d_out;
  char* ws = (char*)d_ws;

  // ---- workspace layout (bytes) ----
  // persistent through phase 2: yh, yl, xh [16384,768] f16 + vT [8][768][2048] f16
  const size_t SZ = 25165824;      // 16384*768*2
  f16* yh = (f16*)(ws + 0 * SZ);
  f16* yl = (f16*)(ws + 1 * SZ);
  f16* xh = (f16*)(ws + 2 * SZ);
  f16* vT = (f16*)(ws + 3 * SZ);
  const size_t PERS = 4 * SZ;      // 100663296
  // phase-1 temps (dead after projections); scores slabs overlay them
  const size_t WT = 1179648;       // 768*768 f16
  f16* xl   = (f16*)(ws + PERS);
  f16* wqTh = (f16*)(ws + PERS + SZ);
  f16* wqTl = (f16*)(ws + PERS + SZ + 1 * WT);
  f16* wkTh = (f16*)(ws + PERS + SZ + 2 * WT);
  f16* wkTl = (f16*)(ws + PERS + SZ + 3 * WT);
  f16* mtH  = (f16*)(ws + PERS + SZ + 4 * WT);
  f16* mtL  = (f16*)(ws + PERS + SZ + 5 * WT);
  f16* wvh  = (f16*)(ws + PERS + SZ + 6 * WT);
  float* scores = (float*)(ws + PERS);

  long avail = (long)ws_size - (long)PERS;
  int nb = (int)(avail / 16777216);  // fp32 [2048,2048] score slabs that fit
  if (nb < 1) nb = 1;
  if (nb > 8) nb = 8;

  // ---- phase 1 ----
  prep_kernel<<<13152, 256, 0, stream>>>(
      (const float4*)x, (const float4*)Wv, Wq, Wk,
      (uint2*)xh, (uint2*)xl, (uint2*)wvh, wqTh, wqTl, wkTh, wkTl);

  // M^T[d'][d] = sum_e WkT[d'][e] * WqT[d][e]  (3-term, f16 pair out)
  gemm_kernel<2, 2, EPI_PAIR, 0><<<dim3(6, 6, 1), 256, 0, stream>>>(
      wkTh, wkTl, wqTh, wqTl, (void*)mtH, (void*)mtL,
      768, 768, 768, 768, 768, 0, 0, 0, 0, 0, 0);

  // y = (xh+xl) * MT_h^T : [16384,768] -> f16 pair (2-term), XCD-swizzled
  gemm_kernel<2, 1, EPI_PAIR, 1><<<768, 256, 0, stream>>>(
      xh, xl, mtH, nullptr, (void*)yh, (void*)yl,
      768, 768, 768, 0, 768, 0, 0, 0, 0, 6, 128);

  // v = xh * Wv_h^T -> vT f16 transposed (1-term), XCD-swizzled
  gemm_kernel<1, 1, EPI_VT, 1><<<768, 256, 0, stream>>>(
      xh, nullptr, wvh, nullptr, (void*)vT, nullptr,
      768, 768, 768, 0, 0, 0, 0, 0, 0, 6, 128);

  // ---- phase 2: scores -> softmax -> PV ----
  const long RS = 1572864;   // 2048*768 (y/x batch stride, elements)
  const long VTS = 1572864;  // 768*2048
  for (int b0 = 0; b0 < 8; b0 += nb) {
    const int nbg = (8 - b0 < nb) ? (8 - b0) : nb;
    // S = yh * xh^T  (1-term), XCD-swizzled
    gemm_kernel<1, 1, EPI_F32, 1><<<256 * nbg, 256, 0, stream>>>(
        yh + (long)b0 * RS, nullptr, xh + (long)b0 * RS, nullptr,
        (void*)scores, nullptr,
        768, 768, 768, 0, 2048, RS, RS, 0, 4194304L, 16, 16);
    softmax_kernel<<<nbg * 2048, 256, 0, stream>>>(scores);
    // O = P * vT^T  (P f16 rows embedded in fp32 score rows, pitch 4096 elems)
    gemm_kernel<1, 1, EPI_F32, 1><<<96 * nbg, 256, 0, stream>>>(
        (const f16*)scores, nullptr, vT + (long)b0 * VTS, nullptr,
        (void*)(out + (long)b0 * 1572864), nullptr,
        2048, 4096, 2048, 0, 768, 8388608L, VTS, 0, 1572864L, 6, 16);
  }
}